// Round 7
// baseline (153.429 us; speedup 1.0000x reference)
//
#include <hip/hip_runtime.h>
#include <hip/hip_bf16.h>
#include <hip/hip_fp16.h>

// ---------------------------------------------------------------------------
// Multihead attention with flat-reshape head split + mean-threshold mask.
//   B=8 S=1024 D=512 H=8 -> 64 independent attention problems of (1024 x 64);
//   problem (h,b) = 128 consecutive rows of the 8192x512 projected matrix
//   reinterpreted as 1024x64.
// Precision: Q/K path 3-term bf16 split -> fp32-accurate scores. V/P/O fp16.
// Round-7:
//   * k_proj V-path: A staged as (f16)(Yh+Yl) with VECTOR loads/stores
//     (round-6 did 16 scalar cvt + 16 scalar ds_write_u16 per thread/kstep
//     -> V blocks dragged the whole dispatch; 5.2M bank conflicts).
//   * k_attn: 512-thread blocks (8 waves x 16 q), grid (64,8) -> 16 waves/CU
//     (4/SIMD, was 2/SIMD) -> latency overlap; one 16B staging write per
//     thread per buffer; s_setprio(1) around MFMA cluster (T5).
// ---------------------------------------------------------------------------

typedef _Float16 f16;
typedef __attribute__((ext_vector_type(4))) _Float16 f16x4;
typedef __attribute__((ext_vector_type(8))) _Float16 f16x8;
typedef __attribute__((ext_vector_type(8))) short bf16x8;
typedef __attribute__((ext_vector_type(4))) float f32x4;

#define MFMA16(a, b, c) __builtin_amdgcn_mfma_f32_16x16x32_f16((a), (b), (c), 0, 0, 0)
#define MFMAB16(a, b, c) __builtin_amdgcn_mfma_f32_16x16x32_bf16((a), (b), (c), 0, 0, 0)
#define MFMAPV(a, b, c) __builtin_amdgcn_mfma_f32_16x16x16f16((a), (b), (c), 0, 0, 0)

#if defined(__has_builtin) && __has_builtin(__builtin_amdgcn_exp2f)
#define EXPFN(x) __builtin_amdgcn_exp2f(x)
#define QPROJ_SCALE (0.04419417382415922f * 1.4426950408889634f)
#else
#define EXPFN(x) __expf(x)
#define QPROJ_SCALE 0.04419417382415922f
#endif

__device__ __forceinline__ float b2f(short s) {
  return __uint_as_float(((unsigned)(unsigned short)s) << 16);
}

__device__ __forceinline__ void splitbf(float v, short& h, short& l) {
  unsigned short hu = __bfloat16_as_ushort(__float2bfloat16(v));
  h = (short)hu;
  float hf = __uint_as_float(((unsigned)hu) << 16);
  l = (short)__bfloat16_as_ushort(__float2bfloat16(v - hf));
}

// --------------------------- weight transpose+convert ----------------------
__global__ void k_wt(const float* __restrict__ w0, const float* __restrict__ w1,
                     const float* __restrict__ w2, const float* __restrict__ w3,
                     short* __restrict__ qh, short* __restrict__ ql,
                     short* __restrict__ kh, short* __restrict__ kl,
                     f16* __restrict__ vt, f16* __restrict__ ot) {
  const float* W;
  switch (blockIdx.z) {
    case 0: W = w0; break;
    case 1: W = w1; break;
    case 2: W = w2; break;
    default: W = w3; break;
  }
  __shared__ float t[32][33];
  int bx = blockIdx.x, by = blockIdx.y;
  int tx = threadIdx.x, ty = threadIdx.y;  // 32 x 8
#pragma unroll
  for (int i = 0; i < 32; i += 8)
    t[ty + i][tx] = W[(size_t)(by * 32 + ty + i) * 512 + bx * 32 + tx];
  __syncthreads();
#pragma unroll
  for (int i = 0; i < 32; i += 8) {
    size_t idx = (size_t)(bx * 32 + ty + i) * 512 + by * 32 + tx;
    float v = t[tx][ty + i];
    if (blockIdx.z < 2) {
      short h, l;
      splitbf(v, h, l);
      if (blockIdx.z == 0) { qh[idx] = h; ql[idx] = l; }
      else { kh[idx] = h; kl[idx] = l; }
    } else {
      if (blockIdx.z == 2) vt[idx] = (f16)v;
      else ot[idx] = (f16)v;
    }
  }
}

// ----------------------- input split (x,y -> bf16 hi/lo) -------------------
__global__ __launch_bounds__(256) void k_split(
    const float* __restrict__ x, const float* __restrict__ y,
    short* __restrict__ Xh, short* __restrict__ Xl, short* __restrict__ Yh,
    short* __restrict__ Yl) {
  const float* src = blockIdx.y ? y : x;
  short* dh = blockIdx.y ? Yh : Xh;
  short* dl = blockIdx.y ? Yl : Xl;
  const size_t i = ((size_t)blockIdx.x * 256 + threadIdx.x) * 8;
  float4 a = *(const float4*)(src + i);
  float4 b = *(const float4*)(src + i + 4);
  float v[8] = {a.x, a.y, a.z, a.w, b.x, b.y, b.z, b.w};
  bf16x8 h, l;
#pragma unroll
  for (int j = 0; j < 8; ++j) {
    short hh, ll;
    splitbf(v[j], hh, ll);
    h[j] = hh;
    l[j] = ll;
  }
  *(bf16x8*)(dh + i) = h;
  *(bf16x8*)(dl + i) = l;
}

// ------------------------- plain fp16 GEMM body ----------------------------
template <typename AT, typename OT>
__device__ __forceinline__ void gemm_body(const AT* __restrict__ A,
                                          const f16* __restrict__ WT,
                                          const float* __restrict__ bias,
                                          OT* __restrict__ C, int m0, int n0,
                                          f16 (*As)[40], f16 (*Bs)[40]) {
  const int tid = threadIdx.x;
  const int wv = tid >> 6, lane = tid & 63;
  const int wm = wv >> 1, wn = wv & 1;
  const int l15 = lane & 15, lg = lane >> 4;
  const int sr = tid >> 1, sc = (tid & 1) * 16;

  const f32x4 fzero = {0.f, 0.f, 0.f, 0.f};
  f32x4 acc[4][4];
#pragma unroll
  for (int m = 0; m < 4; ++m)
#pragma unroll
    for (int n = 0; n < 4; ++n) acc[m][n] = fzero;

  for (int k0 = 0; k0 < 512; k0 += 32) {
    {
      const f16* src = (const f16*)A + (size_t)(m0 + sr) * 512 + k0 + sc;
      *(f16x8*)&As[sr][sc] = *(const f16x8*)src;
      *(f16x8*)&As[sr][sc + 8] = *(const f16x8*)(src + 8);
    }
    {
      const f16* src = WT + (size_t)(n0 + sr) * 512 + k0 + sc;
      *(f16x8*)&Bs[sr][sc] = *(const f16x8*)src;
      *(f16x8*)&Bs[sr][sc + 8] = *(const f16x8*)(src + 8);
    }
    __syncthreads();
    f16x8 af[4], bf[4];
#pragma unroll
    for (int m = 0; m < 4; ++m)
      af[m] = *(const f16x8*)&As[wm * 64 + m * 16 + l15][lg * 8];
#pragma unroll
    for (int n = 0; n < 4; ++n)
      bf[n] = *(const f16x8*)&Bs[wn * 64 + n * 16 + l15][lg * 8];
#pragma unroll
    for (int m = 0; m < 4; ++m)
#pragma unroll
      for (int n = 0; n < 4; ++n) acc[m][n] = MFMA16(af[m], bf[n], acc[m][n]);
    __syncthreads();
  }
#pragma unroll
  for (int n = 0; n < 4; ++n) {
    const int col = n0 + wn * 64 + n * 16 + l15;
    const float b = bias[col];
#pragma unroll
    for (int m = 0; m < 4; ++m) {
      const int row = m0 + wm * 64 + m * 16 + lg * 4;
#pragma unroll
      for (int r = 0; r < 4; ++r) {
        float v = acc[m][n][r] + b;
        C[(size_t)(row + r) * 512 + col] = (OT)v;
      }
    }
  }
}

// --------- fp16 GEMM body, A = (f16)(Ah + Al) from bf16 hi/lo pair ---------
__device__ __forceinline__ void gemm_body_hl(const short* __restrict__ Agh,
                                             const short* __restrict__ Agl,
                                             const f16* __restrict__ WT,
                                             const float* __restrict__ bias,
                                             f16* __restrict__ C, int m0,
                                             int n0, f16 (*As)[40],
                                             f16 (*Bs)[40]) {
  const int tid = threadIdx.x;
  const int wv = tid >> 6, lane = tid & 63;
  const int wm = wv >> 1, wn = wv & 1;
  const int l15 = lane & 15, lg = lane >> 4;
  const int sr = tid >> 1, sc = (tid & 1) * 16;

  const f32x4 fzero = {0.f, 0.f, 0.f, 0.f};
  f32x4 acc[4][4];
#pragma unroll
  for (int m = 0; m < 4; ++m)
#pragma unroll
    for (int n = 0; n < 4; ++n) acc[m][n] = fzero;

  for (int k0 = 0; k0 < 512; k0 += 32) {
    {
      const size_t o = (size_t)(m0 + sr) * 512 + k0 + sc;
      bf16x8 h0 = *(const bf16x8*)(Agh + o);
      bf16x8 h1 = *(const bf16x8*)(Agh + o + 8);
      bf16x8 l0 = *(const bf16x8*)(Agl + o);
      bf16x8 l1 = *(const bf16x8*)(Agl + o + 8);
      f16x8 d0v, d1v;
#pragma unroll
      for (int j = 0; j < 8; ++j) {
        d0v[j] = (f16)(b2f(h0[j]) + b2f(l0[j]));
        d1v[j] = (f16)(b2f(h1[j]) + b2f(l1[j]));
      }
      *(f16x8*)&As[sr][sc] = d0v;
      *(f16x8*)&As[sr][sc + 8] = d1v;
    }
    {
      const f16* src = WT + (size_t)(n0 + sr) * 512 + k0 + sc;
      *(f16x8*)&Bs[sr][sc] = *(const f16x8*)src;
      *(f16x8*)&Bs[sr][sc + 8] = *(const f16x8*)(src + 8);
    }
    __syncthreads();
    f16x8 af[4], bf[4];
#pragma unroll
    for (int m = 0; m < 4; ++m)
      af[m] = *(const f16x8*)&As[wm * 64 + m * 16 + l15][lg * 8];
#pragma unroll
    for (int n = 0; n < 4; ++n)
      bf[n] = *(const f16x8*)&Bs[wn * 64 + n * 16 + l15][lg * 8];
#pragma unroll
    for (int m = 0; m < 4; ++m)
#pragma unroll
      for (int n = 0; n < 4; ++n) acc[m][n] = MFMA16(af[m], bf[n], acc[m][n]);
    __syncthreads();
  }
#pragma unroll
  for (int n = 0; n < 4; ++n) {
    const int col = n0 + wn * 64 + n * 16 + l15;
    const float b = bias[col];
#pragma unroll
    for (int m = 0; m < 4; ++m) {
      const int row = m0 + wm * 64 + m * 16 + lg * 4;
#pragma unroll
      for (int r = 0; r < 4; ++r) {
        float v = acc[m][n][r] + b;
        C[(size_t)(row + r) * 512 + col] = (f16)v;
      }
    }
  }
}

__global__ __launch_bounds__(256) void k_gemm_out(const f16* __restrict__ Om,
                                                  const f16* __restrict__ owT,
                                                  const float* __restrict__ ob,
                                                  float* __restrict__ out) {
  __shared__ __align__(16) f16 As[128][40];
  __shared__ __align__(16) f16 Bs[128][40];
  gemm_body<f16, float>(Om, owT, ob, out, blockIdx.y * 128, blockIdx.x * 128,
                        As, Bs);
}

// ---------------- merged projections: Q,K (split) + V (fp16) ---------------
__global__ __launch_bounds__(256) void k_proj(
    const short* __restrict__ Xh, const short* __restrict__ Xl,
    const short* __restrict__ Yh, const short* __restrict__ Yl,
    const short* __restrict__ qwh, const short* __restrict__ qwl,
    const short* __restrict__ kwh, const short* __restrict__ kwl,
    const f16* __restrict__ vwT, const float* __restrict__ qb,
    const float* __restrict__ kbias, const float* __restrict__ vb,
    short* __restrict__ Qh, short* __restrict__ Ql, short* __restrict__ Kh,
    short* __restrict__ Kl, f16* __restrict__ Vm) {
  __shared__ __align__(16) short sm4[4][128][40];  // 40 KB
  const int m0 = blockIdx.y * 128, n0 = blockIdx.x * 128;
  if (blockIdx.z == 2) {
    gemm_body_hl(Yh, Yl, vwT, vb, Vm, m0, n0, (f16(*)[40]) & sm4[0][0][0],
                 (f16(*)[40]) & sm4[1][0][0]);
    return;
  }
  const int z = blockIdx.z;
  const short* Agh = z ? Yh : Xh;
  const short* Agl = z ? Yl : Xl;
  const short* Wh = z ? kwh : qwh;
  const short* Wl = z ? kwl : qwl;
  const float* bias = z ? kbias : qb;
  short* Ch = z ? Kh : Qh;
  short* Cl = z ? Kl : Ql;
  const float osc = z ? 1.f : (float)QPROJ_SCALE;  // Q pre-scaled for attn

  short(*Ah)[40] = sm4[0];
  short(*Al)[40] = sm4[1];
  short(*Bh)[40] = sm4[2];
  short(*Bl)[40] = sm4[3];
  const int tid = threadIdx.x;
  const int wv = tid >> 6, lane = tid & 63;
  const int wm = wv >> 1, wn = wv & 1;
  const int l15 = lane & 15, lg = lane >> 4;
  const int sr = tid >> 1, sc = (tid & 1) * 16;

  const f32x4 fzero = {0.f, 0.f, 0.f, 0.f};
  f32x4 acc[4][4];
#pragma unroll
  for (int m = 0; m < 4; ++m)
#pragma unroll
    for (int n = 0; n < 4; ++n) acc[m][n] = fzero;

  for (int k0 = 0; k0 < 512; k0 += 32) {
    {
      const size_t o = (size_t)(m0 + sr) * 512 + k0 + sc;
      *(bf16x8*)&Ah[sr][sc] = *(const bf16x8*)(Agh + o);
      *(bf16x8*)&Ah[sr][sc + 8] = *(const bf16x8*)(Agh + o + 8);
      *(bf16x8*)&Al[sr][sc] = *(const bf16x8*)(Agl + o);
      *(bf16x8*)&Al[sr][sc + 8] = *(const bf16x8*)(Agl + o + 8);
    }
    {
      const size_t o = (size_t)(n0 + sr) * 512 + k0 + sc;
      *(bf16x8*)&Bh[sr][sc] = *(const bf16x8*)(Wh + o);
      *(bf16x8*)&Bh[sr][sc + 8] = *(const bf16x8*)(Wh + o + 8);
      *(bf16x8*)&Bl[sr][sc] = *(const bf16x8*)(Wl + o);
      *(bf16x8*)&Bl[sr][sc + 8] = *(const bf16x8*)(Wl + o + 8);
    }
    __syncthreads();
    bf16x8 afh[4], afl[4], bfh[4], bfl[4];
#pragma unroll
    for (int m = 0; m < 4; ++m) {
      afh[m] = *(const bf16x8*)&Ah[wm * 64 + m * 16 + l15][lg * 8];
      afl[m] = *(const bf16x8*)&Al[wm * 64 + m * 16 + l15][lg * 8];
    }
#pragma unroll
    for (int n = 0; n < 4; ++n) {
      bfh[n] = *(const bf16x8*)&Bh[wn * 64 + n * 16 + l15][lg * 8];
      bfl[n] = *(const bf16x8*)&Bl[wn * 64 + n * 16 + l15][lg * 8];
    }
#pragma unroll
    for (int m = 0; m < 4; ++m)
#pragma unroll
      for (int n = 0; n < 4; ++n) {
        acc[m][n] = MFMAB16(afh[m], bfh[n], acc[m][n]);
        acc[m][n] = MFMAB16(afh[m], bfl[n], acc[m][n]);
        acc[m][n] = MFMAB16(afl[m], bfh[n], acc[m][n]);
      }
    __syncthreads();
  }
#pragma unroll
  for (int n = 0; n < 4; ++n) {
    const int col = n0 + wn * 64 + n * 16 + l15;
    const float b = bias[col];
#pragma unroll
    for (int m = 0; m < 4; ++m) {
      const int row = m0 + wm * 64 + m * 16 + lg * 4;
#pragma unroll
      for (int r = 0; r < 4; ++r) {
        float v = (acc[m][n][r] + b) * osc;
        short h, l;
        splitbf(v, h, l);
        const size_t idx = (size_t)(row + r) * 512 + col;
        Ch[idx] = h;
        Cl[idx] = l;
      }
    }
  }
}

// ----------------------- V transpose (per problem) -------------------------
// Vm [8192][512] f16 -> Vt [64 p][64 dh][1024 k] f16.
__global__ __launch_bounds__(256) void k_vtr(const f16* __restrict__ Vm,
                                             f16* __restrict__ Vt) {
  const int p = blockIdx.y;
  const int j0 = blockIdx.x * 16;
  __shared__ f16 L[16][520];
  const int tid = threadIdx.x;
#pragma unroll
  for (int it = 0; it < 4; ++it) {
    int idx = it * 256 + tid;
    int row = idx >> 6, oct = idx & 63;
    *(f16x8*)&L[row][oct * 8] =
        *(const f16x8*)&Vm[(size_t)(p * 128 + j0 + row) * 512 + oct * 8];
  }
  __syncthreads();
#pragma unroll
  for (int it = 0; it < 4; ++it) {
    int idx = it * 256 + tid;
    int dh = idx >> 4, j = idx & 15;
    f16x8 v;
#pragma unroll
    for (int g = 0; g < 8; ++g) v[g] = L[j][g * 64 + dh];
    *(f16x8*)&Vt[((size_t)p * 64 + dh) * 1024 + (j0 + j) * 8] = v;
  }
}

// ------------------- K column-mean (for mean-threshold) --------------------
__global__ __launch_bounds__(256) void k_kmean(const short* __restrict__ Kh,
                                               const short* __restrict__ Kl,
                                               float* __restrict__ Kmean) {
  const int p = blockIdx.x;
  const int t = threadIdx.x;
  const int dh = t & 63, kg = t >> 6;
  const short* hp = Kh + (size_t)p * 65536 + dh;
  const short* lp = Kl + (size_t)p * 65536 + dh;
  float s = 0.f;
  for (int k = kg * 256; k < (kg + 1) * 256; ++k)
    s += b2f(hp[(size_t)k * 64]) + b2f(lp[(size_t)k * 64]);
  __shared__ float red[4][64];
  red[kg][dh] = s;
  __syncthreads();
  if (t < 64)
    Kmean[p * 64 + t] =
        (red[0][t] + red[1][t] + red[2][t] + red[3][t]) * (1.f / 1024.f);
}

// ------------------------------- attention ---------------------------------
// grid (64 problems, 8 q-tiles), 512 threads = 8 waves, ONE 16-q group/wave.
// 2 blocks/CU -> 16 waves/CU (4/SIMD). Double-buffered LDS, one barrier per
// 64-key chunk; one 16B staging write per thread per buffer; setprio around
// MFMA cluster. Q pre-scaled by QPROJ_SCALE; den via ones-column MFMA.
#define LOADREG(cc)                              \
  {                                              \
    rh = *(const bf16x8*)(KhSrc + (cc) * 4096);  \
    rl = *(const bf16x8*)(KlSrc + (cc) * 4096);  \
    rv = *(const f16x8*)(VSrc + (cc) * 64);      \
  }
#define STOREBUF(b)                      \
  {                                      \
    *(bf16x8*)&KhS[b][skey][sslot] = rh; \
    *(bf16x8*)&KlS[b][skey][sslot] = rl; \
    *(f16x8*)&Vs[b][skey][sslot] = rv;   \
  }

__global__ __launch_bounds__(512, 4) void k_attn(
    const short* __restrict__ Qh, const short* __restrict__ Ql,
    const short* __restrict__ Kh, const short* __restrict__ Kl,
    const f16* __restrict__ Vt, const float* __restrict__ Kmean,
    f16* __restrict__ Om) {
  constexpr int S = 1024, DH = 64;
  const int p = blockIdx.x;
  const int qt = blockIdx.y;
  const size_t pb = (size_t)p * S * DH;
  const short* Qhp = Qh + pb;
  const short* Qlp = Ql + pb;
  const short* Khp = Kh + pb;
  const short* Klp = Kl + pb;
  const f16* Vtp = Vt + pb;  // [64 dh][1024 k]
  f16* Op = Om + pb;

  const int tid = threadIdx.x;
  const int w = tid >> 6, lane = tid & 63;
  const int l15 = lane & 15, lg = lane >> 4;

  __shared__ __align__(16) short KhS[2][64][64];
  __shared__ __align__(16) short KlS[2][64][64];
  __shared__ __align__(16) f16 Vs[2][64][64];  // 48 KB total

  // staging: thread -> one 16B slot per buffer; slot XOR-swizzled by row
  const int skey = tid >> 3;        // 0..63 row
  const int slot8 = tid & 7;        // 0..7 16B slot
  const int sslot = (slot8 ^ (skey & 7)) * 8;
  const short* KhSrc = Khp + skey * 64 + slot8 * 8;
  const short* KlSrc = Klp + skey * 64 + slot8 * 8;
  const f16* VSrc = Vtp + (size_t)skey * 1024 + slot8 * 8;

  bf16x8 rh, rl;
  f16x8 rv;
  LOADREG(0);
  STOREBUF(0);  // visible to all after iter-0 barrier
  LOADREG(1);

  // this wave's 16-q group (Q pre-scaled by QPROJ_SCALE)
  const int qrow = qt * 128 + w * 16;
  const size_t qo = (size_t)(qrow + l15) * DH + lg * 8;
  bf16x8 qh0 = *(const bf16x8*)(Qhp + qo);
  bf16x8 ql0 = *(const bf16x8*)(Qlp + qo);
  bf16x8 qh1 = *(const bf16x8*)(Qhp + qo + 32);
  bf16x8 ql1 = *(const bf16x8*)(Qlp + qo + 32);

  // threshold: mean_q = Qscaled_q . Kmean (consistent scale with scores)
  const float* kmp = Kmean + p * 64;
  float4 km0a = *(const float4*)(kmp + lg * 8);
  float4 km0b = *(const float4*)(kmp + lg * 8 + 4);
  float4 km1a = *(const float4*)(kmp + 32 + lg * 8);
  float4 km1b = *(const float4*)(kmp + 32 + lg * 8 + 4);
  float km0[8] = {km0a.x, km0a.y, km0a.z, km0a.w,
                  km0b.x, km0b.y, km0b.z, km0b.w};
  float km1[8] = {km1a.x, km1a.y, km1a.z, km1a.w,
                  km1b.x, km1b.y, km1b.z, km1b.w};
  float sm = 0.f;
#pragma unroll
  for (int j = 0; j < 8; ++j) {
    sm += (b2f(qh0[j]) + b2f(ql0[j])) * km0[j] +
          (b2f(qh1[j]) + b2f(ql1[j])) * km1[j];
  }
  sm += __shfl_xor(sm, 16);
  sm += __shfl_xor(sm, 32);

  const f32x4 fz = {0.f, 0.f, 0.f, 0.f};
  const f16x4 kones = {(f16)1.f, (f16)1.f, (f16)1.f, (f16)1.f};
  f32x4 oac[4];
#pragma unroll
  for (int d = 0; d < 4; ++d) oac[d] = fz;
  f32x4 od = fz;

  for (int c = 0; c < 16; ++c) {
    __syncthreads();  // buf[c&1] writes (iter c-1) + buf[(c+1)&1] reads done
    const int cb = c & 1;
    if (c < 15) STOREBUF(cb ^ 1);  // regs hold chunk c+1
    if (c < 14) LOADREG(c + 2);
    __builtin_amdgcn_s_setprio(1);
#pragma unroll
    for (int t = 0; t < 4; ++t) {
      const int krow = t * 16 + l15;
      const int ksw = krow & 7;
      bf16x8 kh0 = *(const bf16x8*)&KhS[cb][krow][(lg ^ ksw) * 8];
      bf16x8 kh1 = *(const bf16x8*)&KhS[cb][krow][((4 + lg) ^ ksw) * 8];
      bf16x8 kl0 = *(const bf16x8*)&KlS[cb][krow][(lg ^ ksw) * 8];
      bf16x8 kl1 = *(const bf16x8*)&KlS[cb][krow][((4 + lg) ^ ksw) * 8];
      f32x4 a = fz;
      a = MFMAB16(kh0, qh0, a);
      a = MFMAB16(kh1, qh1, a);
      a = MFMAB16(kh0, ql0, a);
      a = MFMAB16(kl0, qh0, a);
      a = MFMAB16(kh1, ql1, a);
      a = MFMAB16(kl1, qh1, a);
      f16x4 pf;
#pragma unroll
      for (int r = 0; r < 4; ++r) {
        float v = a[r];
        float e = (v > sm) ? EXPFN(v) : 0.f;
        pf[r] = (f16)e;
      }
      od = MFMAPV(kones, pf, od);  // den: ones-column MFMA
#pragma unroll
      for (int d0 = 0; d0 < 4; ++d0) {
        const int vrow = d0 * 16 + l15;
        const int vsw = vrow & 7;
        f16x4 va = *(const f16x4*)&Vs[cb][vrow]
                                     [(((t * 2 + (lg >> 1)) ^ vsw) * 8) +
                                      (lg & 1) * 4];
        oac[d0] = MFMAPV(va, pf, oac[d0]);
      }
    }
    __builtin_amdgcn_s_setprio(0);
  }

  const float inv = 1.f / od[0];  // all 4 regs equal (sum over all k)
#pragma unroll
  for (int d0 = 0; d0 < 4; ++d0) {
    f16x4 o0;
#pragma unroll
    for (int r = 0; r < 4; ++r) o0[r] = (f16)(oac[d0][r] * inv);
    *(f16x4*)&Op[(size_t)(qrow + l15) * DH + d0 * 16 + lg * 4] = o0;
  }
}

// ------------------------------- launcher ----------------------------------
extern "C" void kernel_launch(void* const* d_in, const int* in_sizes, int n_in,
                              void* d_out, int out_size, void* d_ws,
                              size_t ws_size, hipStream_t stream) {
  const float* x = (const float*)d_in[0];
  const float* y = (const float*)d_in[1];
  const float* qw = (const float*)d_in[2];
  const float* qb = (const float*)d_in[3];
  const float* kw = (const float*)d_in[4];
  const float* kbias = (const float*)d_in[5];
  const float* vw = (const float*)d_in[6];
  const float* vb = (const float*)d_in[7];
  const float* ow = (const float*)d_in[8];
  const float* ob = (const float*)d_in[9];
  float* out = (float*)d_out;

  char* ws = (char*)d_ws;
  const size_t WT_B = 512ull * 512 * 2;    // 512 KB
  const size_t MAT_B = 8192ull * 512 * 2;  // 8 MB
  short* qwhT = (short*)(ws + 0 * WT_B);
  short* qwlT = (short*)(ws + 1 * WT_B);
  short* kwhT = (short*)(ws + 2 * WT_B);
  short* kwlT = (short*)(ws + 3 * WT_B);
  f16* vwT = (f16*)(ws + 4 * WT_B);
  f16* owT = (f16*)(ws + 5 * WT_B);
  char* m = ws + 6 * WT_B;
  short* Qh = (short*)(m + 0 * MAT_B);
  short* Ql = (short*)(m + 1 * MAT_B);
  short* Kh = (short*)(m + 2 * MAT_B);
  short* Kl = (short*)(m + 3 * MAT_B);
  f16* Vm = (f16*)(m + 4 * MAT_B);
  short* Xh = (short*)(m + 5 * MAT_B);
  short* Xl = (short*)(m + 6 * MAT_B);
  short* Yh = (short*)(m + 7 * MAT_B);
  short* Yl = (short*)(m + 8 * MAT_B);  // 75 MB total
  // dead-buffer aliases (stream order makes these safe):
  f16* Vtr = (f16*)Xh;        // k_vtr runs after k_proj (Xh consumed)
  f16* Om = (f16*)Yh;         // k_attn runs after k_proj (Yh consumed)
  float* Kmean = (float*)Yl;  // k_kmean runs after k_proj (Yl consumed)

  hipLaunchKernelGGL(k_wt, dim3(16, 16, 4), dim3(32, 8), 0, stream, qw, kw, vw,
                     ow, qwhT, qwlT, kwhT, kwlT, vwT, owT);
  hipLaunchKernelGGL(k_split, dim3(2048, 2), dim3(256), 0, stream, x, y, Xh,
                     Xl, Yh, Yl);
  hipLaunchKernelGGL(k_proj, dim3(4, 64, 3), dim3(256), 0, stream, Xh, Xl, Yh,
                     Yl, qwhT, qwlT, kwhT, kwlT, vwT, qb, kbias, vb, Qh, Ql,
                     Kh, Kl, Vm);
  hipLaunchKernelGGL(k_kmean, dim3(64), dim3(256), 0, stream, Kh, Kl, Kmean);
  hipLaunchKernelGGL(k_vtr, dim3(8, 64), dim3(256), 0, stream, Vm, Vtr);
  hipLaunchKernelGGL(k_attn, dim3(64, 8), dim3(512), 0, stream, Qh, Ql, Kh, Kl,
                     Vtr, Kmean, Om);
  hipLaunchKernelGGL(k_gemm_out, dim3(4, 64), dim3(256), 0, stream, Om, owT,
                     ob, out);
}

// Round 8
// 141.597 us; speedup vs baseline: 1.0836x; 1.0836x over previous
//
#include <hip/hip_runtime.h>
#include <hip/hip_bf16.h>
#include <hip/hip_fp16.h>

// ---------------------------------------------------------------------------
// Multihead attention with flat-reshape head split + mean-threshold mask.
//   B=8 S=1024 D=512 H=8 -> 64 independent attention problems of (1024 x 64);
//   problem (h,b) = 128 consecutive rows of the 8192x512 projected matrix
//   reinterpreted as 1024x64.
// Precision: Q/K path 3-term bf16 split -> fp32-accurate scores. V/P/O fp16.
// Round-8:
//   * k_proj rebuilt on the m97 recipe: global_load_lds (16B, async DMA, no
//     reg round-trip / no ds_write VALU) into unpadded [128][32] LDS; LDS
//     reads conflict-free via slot ^= (row>>1)&3 swizzle applied on BOTH the
//     pre-swizzled global source and the ds_read (rule #21). One wave per
//     stream. Round-7: 60 us @ 19% MfmaUtil, 5.2M bank conflicts.
//   * V projection joins the same path via f16 Ym (written by k_split);
//     k_gemm_out shares the same gll-staged body.
//   * k_kmean kernel deleted: K column sums reduced deterministically in the
//     k_proj (z=1) epilogue -> Kpart[p][4][64]; k_attn sums the 4 partials.
// ---------------------------------------------------------------------------

typedef _Float16 f16;
typedef __attribute__((ext_vector_type(4))) _Float16 f16x4;
typedef __attribute__((ext_vector_type(8))) _Float16 f16x8;
typedef __attribute__((ext_vector_type(8))) short bf16x8;
typedef __attribute__((ext_vector_type(4))) float f32x4;

#define MFMA16(a, b, c) __builtin_amdgcn_mfma_f32_16x16x32_f16((a), (b), (c), 0, 0, 0)
#define MFMAB16(a, b, c) __builtin_amdgcn_mfma_f32_16x16x32_bf16((a), (b), (c), 0, 0, 0)
#define MFMAPV(a, b, c) __builtin_amdgcn_mfma_f32_16x16x16f16((a), (b), (c), 0, 0, 0)

#if defined(__has_builtin) && __has_builtin(__builtin_amdgcn_exp2f)
#define EXPFN(x) __builtin_amdgcn_exp2f(x)
#define QPROJ_SCALE (0.04419417382415922f * 1.4426950408889634f)
#else
#define EXPFN(x) __expf(x)
#define QPROJ_SCALE 0.04419417382415922f
#endif

// async global->LDS, 16B per lane; LDS dst = wave-uniform base + lane*16
#define GLL16(gp, lp)                                       \
  __builtin_amdgcn_global_load_lds(                         \
      (const __attribute__((address_space(1))) void*)(gp),  \
      (__attribute__((address_space(3))) void*)(lp), 16, 0, 0)

__device__ __forceinline__ float b2f(short s) {
  return __uint_as_float(((unsigned)(unsigned short)s) << 16);
}

__device__ __forceinline__ void splitbf(float v, short& h, short& l) {
  unsigned short hu = __bfloat16_as_ushort(__float2bfloat16(v));
  h = (short)hu;
  float hf = __uint_as_float(((unsigned)hu) << 16);
  l = (short)__bfloat16_as_ushort(__float2bfloat16(v - hf));
}

// --------------------------- weight transpose+convert ----------------------
__global__ void k_wt(const float* __restrict__ w0, const float* __restrict__ w1,
                     const float* __restrict__ w2, const float* __restrict__ w3,
                     short* __restrict__ qh, short* __restrict__ ql,
                     short* __restrict__ kh, short* __restrict__ kl,
                     f16* __restrict__ vt, f16* __restrict__ ot) {
  const float* W;
  switch (blockIdx.z) {
    case 0: W = w0; break;
    case 1: W = w1; break;
    case 2: W = w2; break;
    default: W = w3; break;
  }
  __shared__ float t[32][33];
  int bx = blockIdx.x, by = blockIdx.y;
  int tx = threadIdx.x, ty = threadIdx.y;  // 32 x 8
#pragma unroll
  for (int i = 0; i < 32; i += 8)
    t[ty + i][tx] = W[(size_t)(by * 32 + ty + i) * 512 + bx * 32 + tx];
  __syncthreads();
#pragma unroll
  for (int i = 0; i < 32; i += 8) {
    size_t idx = (size_t)(bx * 32 + ty + i) * 512 + by * 32 + tx;
    float v = t[tx][ty + i];
    if (blockIdx.z < 2) {
      short h, l;
      splitbf(v, h, l);
      if (blockIdx.z == 0) { qh[idx] = h; ql[idx] = l; }
      else { kh[idx] = h; kl[idx] = l; }
    } else {
      if (blockIdx.z == 2) vt[idx] = (f16)v;
      else ot[idx] = (f16)v;
    }
  }
}

// ------------------ input split (x,y -> bf16 hi/lo; y -> f16) --------------
__global__ __launch_bounds__(256) void k_split(
    const float* __restrict__ x, const float* __restrict__ y,
    short* __restrict__ Xh, short* __restrict__ Xl, short* __restrict__ Yh,
    short* __restrict__ Yl, f16* __restrict__ Ym) {
  const float* src = blockIdx.y ? y : x;
  short* dh = blockIdx.y ? Yh : Xh;
  short* dl = blockIdx.y ? Yl : Xl;
  const size_t i = ((size_t)blockIdx.x * 256 + threadIdx.x) * 8;
  float4 a = *(const float4*)(src + i);
  float4 b = *(const float4*)(src + i + 4);
  float v[8] = {a.x, a.y, a.z, a.w, b.x, b.y, b.z, b.w};
  bf16x8 h, l;
#pragma unroll
  for (int j = 0; j < 8; ++j) {
    short hh, ll;
    splitbf(v[j], hh, ll);
    h[j] = hh;
    l[j] = ll;
  }
  *(bf16x8*)(dh + i) = h;
  *(bf16x8*)(dl + i) = l;
  if (blockIdx.y) {
    f16x8 m8;
#pragma unroll
    for (int j = 0; j < 8; ++j) m8[j] = (f16)v[j];
    *(f16x8*)(Ym + i) = m8;
  }
}

// ---------------- gll-staged plain f16 GEMM body (V-proj, out-GEMM) --------
// C[8192][512] = A[8192][512] @ WT^T + bias; [128][32] LDS, swizzled slots.
template <typename OT>
__device__ __forceinline__ void gemm16_gll(const f16* __restrict__ A,
                                           const f16* __restrict__ WT,
                                           const float* __restrict__ bias,
                                           OT* __restrict__ C, int m0, int n0,
                                           f16 (*As)[32], f16 (*Bs)[32]) {
  const int tid = threadIdx.x;
  const int wv = tid >> 6, lane = tid & 63;
  const int wm = wv >> 1, wn = wv & 1;
  const int l15 = lane & 15, lg = lane >> 4;
  const int srow = lane >> 2, sslot = lane & 3;

  const f16* gsb = (wv < 2) ? A : WT;
  const int rb = (wv < 2) ? m0 : n0;
  f16(*ldsb)[32] = (wv < 2) ? As : Bs;
  const int half = (wv & 1) * 64;

  const f32x4 fz = {0.f, 0.f, 0.f, 0.f};
  f32x4 acc[4][4];
#pragma unroll
  for (int m = 0; m < 4; ++m)
#pragma unroll
    for (int n = 0; n < 4; ++n) acc[m][n] = fz;

  for (int k0 = 0; k0 < 512; k0 += 32) {
    __syncthreads();  // prev reads done
#pragma unroll
    for (int j = 0; j < 4; ++j) {
      const int row = half + j * 16 + srow;
      const int slog = sslot ^ ((row >> 1) & 3);
      GLL16(gsb + (size_t)(rb + row) * 512 + k0 + slog * 8,
            &ldsb[half + j * 16][0]);
    }
    __syncthreads();  // drains vmcnt -> LDS ready
    f16x8 af[4], bf[4];
#pragma unroll
    for (int m = 0; m < 4; ++m) {
      const int r = wm * 64 + m * 16 + l15;
      af[m] = *(const f16x8*)&As[r][(lg ^ ((r >> 1) & 3)) * 8];
    }
#pragma unroll
    for (int n = 0; n < 4; ++n) {
      const int r = wn * 64 + n * 16 + l15;
      bf[n] = *(const f16x8*)&Bs[r][(lg ^ ((r >> 1) & 3)) * 8];
    }
#pragma unroll
    for (int m = 0; m < 4; ++m)
#pragma unroll
      for (int n = 0; n < 4; ++n) acc[m][n] = MFMA16(af[m], bf[n], acc[m][n]);
  }
#pragma unroll
  for (int n = 0; n < 4; ++n) {
    const int col = n0 + wn * 64 + n * 16 + l15;
    const float b = bias[col];
#pragma unroll
    for (int m = 0; m < 4; ++m) {
      const int row = m0 + wm * 64 + m * 16 + lg * 4;
#pragma unroll
      for (int r = 0; r < 4; ++r)
        C[(size_t)(row + r) * 512 + col] = (OT)(acc[m][n][r] + b);
    }
  }
}

__global__ __launch_bounds__(256) void k_gemm_out(const f16* __restrict__ Om,
                                                  const f16* __restrict__ owT,
                                                  const float* __restrict__ ob,
                                                  float* __restrict__ out) {
  __shared__ __align__(16) f16 As[128][32];
  __shared__ __align__(16) f16 Bs[128][32];
  gemm16_gll<float>(Om, owT, ob, out, blockIdx.y * 128, blockIdx.x * 128, As,
                    Bs);
}

// ---------------- merged projections: Q,K (split) + V (f16) ----------------
__global__ __launch_bounds__(256) void k_proj(
    const short* __restrict__ Xh, const short* __restrict__ Xl,
    const short* __restrict__ Yh, const short* __restrict__ Yl,
    const f16* __restrict__ Ym, const short* __restrict__ qwh,
    const short* __restrict__ qwl, const short* __restrict__ kwh,
    const short* __restrict__ kwl, const f16* __restrict__ vwT,
    const float* __restrict__ qb, const float* __restrict__ kbias,
    const float* __restrict__ vb, short* __restrict__ Qh,
    short* __restrict__ Ql, short* __restrict__ Kh, short* __restrict__ Kl,
    f16* __restrict__ Vm, float* __restrict__ Kpart) {
  __shared__ __align__(16) short sm4[4][128][32];  // 32 KB
  const int m0 = blockIdx.y * 128, n0 = blockIdx.x * 128;
  const int z = blockIdx.z;
  if (z == 2) {
    gemm16_gll<f16>(Ym, vwT, vb, Vm, m0, n0, (f16(*)[32]) & sm4[0][0][0],
                    (f16(*)[32]) & sm4[1][0][0]);
    return;
  }
  const short* Agh = z ? Yh : Xh;
  const short* Agl = z ? Yl : Xl;
  const short* Wh = z ? kwh : qwh;
  const short* Wl = z ? kwl : qwl;
  const float* bias = z ? kbias : qb;
  short* Ch = z ? Kh : Qh;
  short* Cl = z ? Kl : Ql;
  const float osc = z ? 1.f : (float)QPROJ_SCALE;  // Q pre-scaled for attn

  const int tid = threadIdx.x;
  const int wv = tid >> 6, lane = tid & 63;
  const int wm = wv >> 1, wn = wv & 1;
  const int l15 = lane & 15, lg = lane >> 4;
  const int srow = lane >> 2, sslot = lane & 3;

  // wave wv stages stream wv: 0=A-hi, 1=A-lo, 2=B-hi, 3=B-lo (8 KB each)
  const short* gsb = (wv == 0) ? Agh : (wv == 1) ? Agl : (wv == 2) ? Wh : Wl;
  const int rb = (wv < 2) ? m0 : n0;
  short(*ldsb)[32] = sm4[wv];
  short(*Ah)[32] = sm4[0];
  short(*Al)[32] = sm4[1];
  short(*Bh)[32] = sm4[2];
  short(*Bl)[32] = sm4[3];

  const f32x4 fz = {0.f, 0.f, 0.f, 0.f};
  f32x4 acc[4][4];
#pragma unroll
  for (int m = 0; m < 4; ++m)
#pragma unroll
    for (int n = 0; n < 4; ++n) acc[m][n] = fz;

  for (int k0 = 0; k0 < 512; k0 += 32) {
    __syncthreads();  // previous tile's reads complete
#pragma unroll
    for (int j = 0; j < 8; ++j) {
      const int row = j * 16 + srow;
      const int slog = sslot ^ ((row >> 1) & 3);
      GLL16(gsb + (size_t)(rb + row) * 512 + k0 + slog * 8, &ldsb[j * 16][0]);
    }
    __syncthreads();  // drains vmcnt -> LDS ready
    bf16x8 afh[4], afl[4], bfh[4], bfl[4];
#pragma unroll
    for (int m = 0; m < 4; ++m) {
      const int r = wm * 64 + m * 16 + l15;
      const int sl = (lg ^ ((r >> 1) & 3)) * 8;
      afh[m] = *(const bf16x8*)&Ah[r][sl];
      afl[m] = *(const bf16x8*)&Al[r][sl];
    }
#pragma unroll
    for (int n = 0; n < 4; ++n) {
      const int r = wn * 64 + n * 16 + l15;
      const int sl = (lg ^ ((r >> 1) & 3)) * 8;
      bfh[n] = *(const bf16x8*)&Bh[r][sl];
      bfl[n] = *(const bf16x8*)&Bl[r][sl];
    }
#pragma unroll
    for (int m = 0; m < 4; ++m)
#pragma unroll
      for (int n = 0; n < 4; ++n) {
        acc[m][n] = MFMAB16(afh[m], bfh[n], acc[m][n]);
        acc[m][n] = MFMAB16(afh[m], bfl[n], acc[m][n]);
        acc[m][n] = MFMAB16(afl[m], bfh[n], acc[m][n]);
      }
  }
  // epilogue: split-bf16 output (+ deterministic K column partial sums)
  float csum[4];
#pragma unroll
  for (int n = 0; n < 4; ++n) {
    const int col = n0 + wn * 64 + n * 16 + l15;
    const float b = bias[col];
    csum[n] = 16.f * b;
#pragma unroll
    for (int m = 0; m < 4; ++m) {
      const int row = m0 + wm * 64 + m * 16 + lg * 4;
#pragma unroll
      for (int r = 0; r < 4; ++r) {
        const float vraw = acc[m][n][r] + b;
        csum[n] += acc[m][n][r];
        short h, l;
        splitbf(vraw * osc, h, l);
        const size_t idx = (size_t)(row + r) * 512 + col;
        Ch[idx] = h;
        Cl[idx] = l;
      }
    }
  }
  if (z == 1) {
    // block-local column reduction (deterministic): 128 cols x 8 contributors
    float* cred = (float*)&sm4[0][0][0];
    __syncthreads();  // all waves done with LDS tiles
#pragma unroll
    for (int n = 0; n < 4; ++n)
      cred[(wn * 64 + n * 16 + l15) * 8 + wm * 4 + lg] = csum[n];
    __syncthreads();
    if (tid < 64) {
      float s = 0.f;
#pragma unroll
      for (int j = 0; j < 8; ++j)
        s += cred[tid * 8 + j] + cred[(tid + 64) * 8 + j];
      Kpart[((size_t)blockIdx.y * 4 + blockIdx.x) * 64 + tid] = s;
    }
  }
}

// ----------------------- V transpose (per problem) -------------------------
// Vm [8192][512] f16 -> Vt [64 p][64 dh][1024 k] f16.
__global__ __launch_bounds__(256) void k_vtr(const f16* __restrict__ Vm,
                                             f16* __restrict__ Vt) {
  const int p = blockIdx.y;
  const int j0 = blockIdx.x * 16;
  __shared__ f16 L[16][520];
  const int tid = threadIdx.x;
#pragma unroll
  for (int it = 0; it < 4; ++it) {
    int idx = it * 256 + tid;
    int row = idx >> 6, oct = idx & 63;
    *(f16x8*)&L[row][oct * 8] =
        *(const f16x8*)&Vm[(size_t)(p * 128 + j0 + row) * 512 + oct * 8];
  }
  __syncthreads();
#pragma unroll
  for (int it = 0; it < 4; ++it) {
    int idx = it * 256 + tid;
    int dh = idx >> 4, j = idx & 15;
    f16x8 v;
#pragma unroll
    for (int g = 0; g < 8; ++g) v[g] = L[j][g * 64 + dh];
    *(f16x8*)&Vt[((size_t)p * 64 + dh) * 1024 + (j0 + j) * 8] = v;
  }
}

// ------------------------------- attention ---------------------------------
// grid (64 problems, 8 q-tiles), 512 threads = 8 waves, ONE 16-q group/wave.
// Double-buffered LDS, one barrier per 64-key chunk; setprio around MFMA.
// Threshold mean from Kpart partial sums (x 1/1024).
#define LOADREG(cc)                              \
  {                                              \
    rh = *(const bf16x8*)(KhSrc + (cc) * 4096);  \
    rl = *(const bf16x8*)(KlSrc + (cc) * 4096);  \
    rv = *(const f16x8*)(VSrc + (cc) * 64);      \
  }
#define STOREBUF(b)                      \
  {                                      \
    *(bf16x8*)&KhS[b][skey][sslot] = rh; \
    *(bf16x8*)&KlS[b][skey][sslot] = rl; \
    *(f16x8*)&Vs[b][skey][sslot] = rv;   \
  }

__global__ __launch_bounds__(512, 4) void k_attn(
    const short* __restrict__ Qh, const short* __restrict__ Ql,
    const short* __restrict__ Kh, const short* __restrict__ Kl,
    const f16* __restrict__ Vt, const float* __restrict__ Kpart,
    f16* __restrict__ Om) {
  constexpr int S = 1024, DH = 64;
  const int p = blockIdx.x;
  const int qt = blockIdx.y;
  const size_t pb = (size_t)p * S * DH;
  const short* Qhp = Qh + pb;
  const short* Qlp = Ql + pb;
  const short* Khp = Kh + pb;
  const short* Klp = Kl + pb;
  const f16* Vtp = Vt + pb;  // [64 dh][1024 k]
  f16* Op = Om + pb;

  const int tid = threadIdx.x;
  const int w = tid >> 6, lane = tid & 63;
  const int l15 = lane & 15, lg = lane >> 4;

  __shared__ __align__(16) short KhS[2][64][64];
  __shared__ __align__(16) short KlS[2][64][64];
  __shared__ __align__(16) f16 Vs[2][64][64];  // 48 KB total

  const int skey = tid >> 3;
  const int slot8 = tid & 7;
  const int sslot = (slot8 ^ (skey & 7)) * 8;
  const short* KhSrc = Khp + skey * 64 + slot8 * 8;
  const short* KlSrc = Klp + skey * 64 + slot8 * 8;
  const f16* VSrc = Vtp + (size_t)skey * 1024 + slot8 * 8;

  bf16x8 rh, rl;
  f16x8 rv;
  LOADREG(0);
  STOREBUF(0);  // visible to all after iter-0 barrier
  LOADREG(1);

  // this wave's 16-q group (Q pre-scaled by QPROJ_SCALE)
  const int qrow = qt * 128 + w * 16;
  const size_t qo = (size_t)(qrow + l15) * DH + lg * 8;
  bf16x8 qh0 = *(const bf16x8*)(Qhp + qo);
  bf16x8 ql0 = *(const bf16x8*)(Qlp + qo);
  bf16x8 qh1 = *(const bf16x8*)(Qhp + qo + 32);
  bf16x8 ql1 = *(const bf16x8*)(Qlp + qo + 32);

  // threshold: mean_q = (Qscaled_q . Ksum) / 1024, Ksum = sum of 4 partials
  const float* kp = Kpart + (size_t)p * 256;
  float km0[8], km1[8];
#pragma unroll
  for (int j = 0; j < 8; ++j) { km0[j] = 0.f; km1[j] = 0.f; }
#pragma unroll
  for (int pt = 0; pt < 4; ++pt) {
    const float* bb = kp + pt * 64;
#pragma unroll
    for (int j = 0; j < 8; ++j) {
      km0[j] += bb[lg * 8 + j];
      km1[j] += bb[32 + lg * 8 + j];
    }
  }
  float sm = 0.f;
#pragma unroll
  for (int j = 0; j < 8; ++j) {
    sm += (b2f(qh0[j]) + b2f(ql0[j])) * km0[j] +
          (b2f(qh1[j]) + b2f(ql1[j])) * km1[j];
  }
  sm += __shfl_xor(sm, 16);
  sm += __shfl_xor(sm, 32);
  sm *= (1.f / 1024.f);

  const f32x4 fz = {0.f, 0.f, 0.f, 0.f};
  const f16x4 kones = {(f16)1.f, (f16)1.f, (f16)1.f, (f16)1.f};
  f32x4 oac[4];
#pragma unroll
  for (int d = 0; d < 4; ++d) oac[d] = fz;
  f32x4 od = fz;

  for (int c = 0; c < 16; ++c) {
    __syncthreads();  // buf[c&1] writes (iter c-1) + buf[(c+1)&1] reads done
    const int cb = c & 1;
    if (c < 15) STOREBUF(cb ^ 1);  // regs hold chunk c+1
    if (c < 14) LOADREG(c + 2);
    __builtin_amdgcn_s_setprio(1);
#pragma unroll
    for (int t = 0; t < 4; ++t) {
      const int krow = t * 16 + l15;
      const int ksw = krow & 7;
      bf16x8 kh0 = *(const bf16x8*)&KhS[cb][krow][(lg ^ ksw) * 8];
      bf16x8 kh1 = *(const bf16x8*)&KhS[cb][krow][((4 + lg) ^ ksw) * 8];
      bf16x8 kl0 = *(const bf16x8*)&KlS[cb][krow][(lg ^ ksw) * 8];
      bf16x8 kl1 = *(const bf16x8*)&KlS[cb][krow][((4 + lg) ^ ksw) * 8];
      f32x4 a = fz;
      a = MFMAB16(kh0, qh0, a);
      a = MFMAB16(kh1, qh1, a);
      a = MFMAB16(kh0, ql0, a);
      a = MFMAB16(kl0, qh0, a);
      a = MFMAB16(kh1, ql1, a);
      a = MFMAB16(kl1, qh1, a);
      f16x4 pf;
#pragma unroll
      for (int r = 0; r < 4; ++r) {
        float v = a[r];
        float e = (v > sm) ? EXPFN(v) : 0.f;
        pf[r] = (f16)e;
      }
      od = MFMAPV(kones, pf, od);  // den: ones-column MFMA
#pragma unroll
      for (int d0 = 0; d0 < 4; ++d0) {
        const int vrow = d0 * 16 + l15;
        const int vsw = vrow & 7;
        f16x4 va = *(const f16x4*)&Vs[cb][vrow]
                                     [(((t * 2 + (lg >> 1)) ^ vsw) * 8) +
                                      (lg & 1) * 4];
        oac[d0] = MFMAPV(va, pf, oac[d0]);
      }
    }
    __builtin_amdgcn_s_setprio(0);
  }

  const float inv = 1.f / od[0];  // all 4 regs equal (sum over all k)
#pragma unroll
  for (int d0 = 0; d0 < 4; ++d0) {
    f16x4 o0;
#pragma unroll
    for (int r = 0; r < 4; ++r) o0[r] = (f16)(oac[d0][r] * inv);
    *(f16x4*)&Op[(size_t)(qrow + l15) * DH + d0 * 16 + lg * 4] = o0;
  }
}

// ------------------------------- launcher ----------------------------------
extern "C" void kernel_launch(void* const* d_in, const int* in_sizes, int n_in,
                              void* d_out, int out_size, void* d_ws,
                              size_t ws_size, hipStream_t stream) {
  const float* x = (const float*)d_in[0];
  const float* y = (const float*)d_in[1];
  const float* qw = (const float*)d_in[2];
  const float* qb = (const float*)d_in[3];
  const float* kw = (const float*)d_in[4];
  const float* kbias = (const float*)d_in[5];
  const float* vw = (const float*)d_in[6];
  const float* vb = (const float*)d_in[7];
  const float* ow = (const float*)d_in[8];
  const float* ob = (const float*)d_in[9];
  float* out = (float*)d_out;

  char* ws = (char*)d_ws;
  const size_t WT_B = 512ull * 512 * 2;    // 512 KB
  const size_t MAT_B = 8192ull * 512 * 2;  // 8 MB
  short* qwhT = (short*)(ws + 0 * WT_B);
  short* qwlT = (short*)(ws + 1 * WT_B);
  short* kwhT = (short*)(ws + 2 * WT_B);
  short* kwlT = (short*)(ws + 3 * WT_B);
  f16* vwT = (f16*)(ws + 4 * WT_B);
  f16* owT = (f16*)(ws + 5 * WT_B);
  char* m = ws + 6 * WT_B;
  short* Qh = (short*)(m + 0 * MAT_B);
  short* Ql = (short*)(m + 1 * MAT_B);
  short* Kh = (short*)(m + 2 * MAT_B);
  short* Kl = (short*)(m + 3 * MAT_B);
  f16* Vm = (f16*)(m + 4 * MAT_B);
  short* Xh = (short*)(m + 5 * MAT_B);
  short* Xl = (short*)(m + 6 * MAT_B);
  short* Yh = (short*)(m + 7 * MAT_B);
  short* Yl = (short*)(m + 8 * MAT_B);
  f16* Ym = (f16*)(m + 9 * MAT_B);
  float* Kpart = (float*)(m + 10 * MAT_B);  // 64 KB; total ~83.1 MB
  // dead-buffer aliases (stream order makes these safe):
  f16* Vtr = (f16*)Xh;  // k_vtr runs after k_proj (Xh consumed)
  f16* Om = (f16*)Yh;   // k_attn runs after k_proj (Yh consumed)

  hipLaunchKernelGGL(k_wt, dim3(16, 16, 4), dim3(32, 8), 0, stream, qw, kw, vw,
                     ow, qwhT, qwlT, kwhT, kwlT, vwT, owT);
  hipLaunchKernelGGL(k_split, dim3(2048, 2), dim3(256), 0, stream, x, y, Xh,
                     Xl, Yh, Yl, Ym);
  hipLaunchKernelGGL(k_proj, dim3(4, 64, 3), dim3(256), 0, stream, Xh, Xl, Yh,
                     Yl, Ym, qwhT, qwlT, kwhT, kwlT, vwT, qb, kbias, vb, Qh,
                     Ql, Kh, Kl, Vm, Kpart);
  hipLaunchKernelGGL(k_vtr, dim3(8, 64), dim3(256), 0, stream, Vm, Vtr);
  hipLaunchKernelGGL(k_attn, dim3(64, 8), dim3(512), 0, stream, Qh, Ql, Kh, Kl,
                     Vtr, Kpart, Om);
  hipLaunchKernelGGL(k_gemm_out, dim3(4, 64), dim3(256), 0, stream, Om, owT,
                     ob, out);
}

// Round 9
// 118.895 us; speedup vs baseline: 1.2905x; 1.1909x over previous
//
#include <hip/hip_runtime.h>
#include <hip/hip_bf16.h>
#include <hip/hip_fp16.h>

// ---------------------------------------------------------------------------
// Multihead attention with flat-reshape head split + mean-threshold mask.
//   B=8 S=1024 D=512 H=8 -> 64 independent attention problems of (1024 x 64);
//   problem (h,b) = 128 consecutive rows of the 8192x512 projected matrix
//   reinterpreted as 1024x64.
// Precision: Q/K path 3-term bf16 split -> fp32-accurate scores. V/P/O fp16.
// Round-9 (perf only, numerics identical):
//   * k_proj / k_gemm_out: double-buffered global_load_lds staging — issue
//     prefetch of k+1 right after the barrier, compute k under it (round-8
//     exposed the full load latency inside each iteration: barrier-issue-
//     drain-compute; 10% occupancy, 18% MfmaUtil at 0 bank conflicts).
//     One barrier per k-step.
//   * XCD-bijective block swizzle (256 = 8x32): the 4 n-tiles of an A-panel
//     + 8 consecutive m-panels land on one XCD L2 -> A fetched once per XCD
//     (round-8: 84.6 MB fetch vs 42 MB unique).
// ---------------------------------------------------------------------------

typedef _Float16 f16;
typedef __attribute__((ext_vector_type(4))) _Float16 f16x4;
typedef __attribute__((ext_vector_type(8))) _Float16 f16x8;
typedef __attribute__((ext_vector_type(8))) short bf16x8;
typedef __attribute__((ext_vector_type(4))) float f32x4;

#define MFMA16(a, b, c) __builtin_amdgcn_mfma_f32_16x16x32_f16((a), (b), (c), 0, 0, 0)
#define MFMAB16(a, b, c) __builtin_amdgcn_mfma_f32_16x16x32_bf16((a), (b), (c), 0, 0, 0)
#define MFMAPV(a, b, c) __builtin_amdgcn_mfma_f32_16x16x16f16((a), (b), (c), 0, 0, 0)

#if defined(__has_builtin) && __has_builtin(__builtin_amdgcn_exp2f)
#define EXPFN(x) __builtin_amdgcn_exp2f(x)
#define QPROJ_SCALE (0.04419417382415922f * 1.4426950408889634f)
#else
#define EXPFN(x) __expf(x)
#define QPROJ_SCALE 0.04419417382415922f
#endif

// async global->LDS, 16B per lane; LDS dst = wave-uniform base + lane*16
#define GLL16(gp, lp)                                       \
  __builtin_amdgcn_global_load_lds(                         \
      (const __attribute__((address_space(1))) void*)(gp),  \
      (__attribute__((address_space(3))) void*)(lp), 16, 0, 0)

__device__ __forceinline__ float b2f(short s) {
  return __uint_as_float(((unsigned)(unsigned short)s) << 16);
}

__device__ __forceinline__ void splitbf(float v, short& h, short& l) {
  unsigned short hu = __bfloat16_as_ushort(__float2bfloat16(v));
  h = (short)hu;
  float hf = __uint_as_float(((unsigned)hu) << 16);
  l = (short)__bfloat16_as_ushort(__float2bfloat16(v - hf));
}

// --------------------------- weight transpose+convert ----------------------
__global__ void k_wt(const float* __restrict__ w0, const float* __restrict__ w1,
                     const float* __restrict__ w2, const float* __restrict__ w3,
                     short* __restrict__ qh, short* __restrict__ ql,
                     short* __restrict__ kh, short* __restrict__ kl,
                     f16* __restrict__ vt, f16* __restrict__ ot) {
  const float* W;
  switch (blockIdx.z) {
    case 0: W = w0; break;
    case 1: W = w1; break;
    case 2: W = w2; break;
    default: W = w3; break;
  }
  __shared__ float t[32][33];
  int bx = blockIdx.x, by = blockIdx.y;
  int tx = threadIdx.x, ty = threadIdx.y;  // 32 x 8
#pragma unroll
  for (int i = 0; i < 32; i += 8)
    t[ty + i][tx] = W[(size_t)(by * 32 + ty + i) * 512 + bx * 32 + tx];
  __syncthreads();
#pragma unroll
  for (int i = 0; i < 32; i += 8) {
    size_t idx = (size_t)(bx * 32 + ty + i) * 512 + by * 32 + tx;
    float v = t[tx][ty + i];
    if (blockIdx.z < 2) {
      short h, l;
      splitbf(v, h, l);
      if (blockIdx.z == 0) { qh[idx] = h; ql[idx] = l; }
      else { kh[idx] = h; kl[idx] = l; }
    } else {
      if (blockIdx.z == 2) vt[idx] = (f16)v;
      else ot[idx] = (f16)v;
    }
  }
}

// ------------------ input split (x,y -> bf16 hi/lo; y -> f16) --------------
__global__ __launch_bounds__(256) void k_split(
    const float* __restrict__ x, const float* __restrict__ y,
    short* __restrict__ Xh, short* __restrict__ Xl, short* __restrict__ Yh,
    short* __restrict__ Yl, f16* __restrict__ Ym) {
  const float* src = blockIdx.y ? y : x;
  short* dh = blockIdx.y ? Yh : Xh;
  short* dl = blockIdx.y ? Yl : Xl;
  const size_t i = ((size_t)blockIdx.x * 256 + threadIdx.x) * 8;
  float4 a = *(const float4*)(src + i);
  float4 b = *(const float4*)(src + i + 4);
  float v[8] = {a.x, a.y, a.z, a.w, b.x, b.y, b.z, b.w};
  bf16x8 h, l;
#pragma unroll
  for (int j = 0; j < 8; ++j) {
    short hh, ll;
    splitbf(v[j], hh, ll);
    h[j] = hh;
    l[j] = ll;
  }
  *(bf16x8*)(dh + i) = h;
  *(bf16x8*)(dl + i) = l;
  if (blockIdx.y) {
    f16x8 m8;
#pragma unroll
    for (int j = 0; j < 8; ++j) m8[j] = (f16)v[j];
    *(f16x8*)(Ym + i) = m8;
  }
}

// ---------- gll-staged, double-buffered f16 GEMM (V-proj, out-GEMM) --------
// C[8192][512] = A @ WT^T + bias; [2][128][32] LDS per operand.
#define GSTAGE(buf, kk)                                              \
  {                                                                  \
    _Pragma("unroll") for (int j = 0; j < 4; ++j) {                  \
      const int rowu = half + j * 16;                                \
      const int row = rowu + srow;                                   \
      const int slog = sslot ^ ((row >> 1) & 3);                     \
      GLL16(gsb + (size_t)(rb + row) * 512 + (kk) + slog * 8,        \
            &ldsb[buf][rowu][0]);                                    \
    }                                                                \
  }

template <typename OT>
__device__ __forceinline__ void gemm16_gll(const f16* __restrict__ A,
                                           const f16* __restrict__ WT,
                                           const float* __restrict__ bias,
                                           OT* __restrict__ C, int m0, int n0,
                                           f16 (*As)[128][32],
                                           f16 (*Bs)[128][32]) {
  const int tid = threadIdx.x;
  const int wv = tid >> 6, lane = tid & 63;
  const int wm = wv >> 1, wn = wv & 1;
  const int l15 = lane & 15, lg = lane >> 4;
  const int srow = lane >> 2, sslot = lane & 3;

  const f16* gsb = (wv < 2) ? A : WT;
  const int rb = (wv < 2) ? m0 : n0;
  f16(*ldsb)[128][32] = (wv < 2) ? As : Bs;
  const int half = (wv & 1) * 64;

  const f32x4 fz = {0.f, 0.f, 0.f, 0.f};
  f32x4 acc[4][4];
#pragma unroll
  for (int m = 0; m < 4; ++m)
#pragma unroll
    for (int n = 0; n < 4; ++n) acc[m][n] = fz;

  GSTAGE(0, 0);  // prologue
  int cur = 0;
  for (int k0 = 0; k0 < 512; k0 += 32) {
    __syncthreads();  // drains prefetch -> buf[cur] ready; prev reads done
    if (k0 < 480) GSTAGE(cur ^ 1, k0 + 32);  // in flight under compute
    f16x8 af[4], bf[4];
#pragma unroll
    for (int m = 0; m < 4; ++m) {
      const int r = wm * 64 + m * 16 + l15;
      af[m] = *(const f16x8*)&As[cur][r][(lg ^ ((r >> 1) & 3)) * 8];
    }
#pragma unroll
    for (int n = 0; n < 4; ++n) {
      const int r = wn * 64 + n * 16 + l15;
      bf[n] = *(const f16x8*)&Bs[cur][r][(lg ^ ((r >> 1) & 3)) * 8];
    }
#pragma unroll
    for (int m = 0; m < 4; ++m)
#pragma unroll
      for (int n = 0; n < 4; ++n) acc[m][n] = MFMA16(af[m], bf[n], acc[m][n]);
    cur ^= 1;
  }
#pragma unroll
  for (int n = 0; n < 4; ++n) {
    const int col = n0 + wn * 64 + n * 16 + l15;
    const float b = bias[col];
#pragma unroll
    for (int m = 0; m < 4; ++m) {
      const int row = m0 + wm * 64 + m * 16 + lg * 4;
#pragma unroll
      for (int r = 0; r < 4; ++r)
        C[(size_t)(row + r) * 512 + col] = (OT)(acc[m][n][r] + b);
    }
  }
}

__global__ __launch_bounds__(256) void k_gemm_out(const f16* __restrict__ Om,
                                                  const f16* __restrict__ owT,
                                                  const float* __restrict__ ob,
                                                  float* __restrict__ out) {
  __shared__ __align__(16) f16 As[2][128][32];
  __shared__ __align__(16) f16 Bs[2][128][32];
  const int lid = blockIdx.x + (blockIdx.y << 2);
  const int swz = ((lid & 7) << 5) + (lid >> 3);  // XCD-bijective (256=8x32)
  gemm16_gll<float>(Om, owT, ob, out, (swz >> 2) * 128, (swz & 3) * 128, As,
                    Bs);
}

// ---------------- merged projections: Q,K (split) + V (f16) ----------------
#define PSTAGE(buf, kk)                                             \
  {                                                                 \
    _Pragma("unroll") for (int j = 0; j < 8; ++j) {                 \
      const int row = j * 16 + srow;                                \
      const int slog = sslot ^ ((row >> 1) & 3);                    \
      GLL16(gsb + (size_t)(rb + row) * 512 + (kk) + slog * 8,       \
            &sm4[buf][wv][j * 16][0]);                              \
    }                                                               \
  }

__global__ __launch_bounds__(256) void k_proj(
    const short* __restrict__ Xh, const short* __restrict__ Xl,
    const short* __restrict__ Yh, const short* __restrict__ Yl,
    const f16* __restrict__ Ym, const short* __restrict__ qwh,
    const short* __restrict__ qwl, const short* __restrict__ kwh,
    const short* __restrict__ kwl, const f16* __restrict__ vwT,
    const float* __restrict__ qb, const float* __restrict__ kbias,
    const float* __restrict__ vb, short* __restrict__ Qh,
    short* __restrict__ Ql, short* __restrict__ Kh, short* __restrict__ Kl,
    f16* __restrict__ Vm, float* __restrict__ Kpart) {
  __shared__ __align__(16) short sm4[2][4][128][32];  // 64 KB (double-buffer)
  const int lid = blockIdx.x + (blockIdx.y << 2);
  const int swz = ((lid & 7) << 5) + (lid >> 3);  // XCD-bijective (256=8x32)
  const int nt = swz & 3, mt = swz >> 2;
  const int m0 = mt * 128, n0 = nt * 128;
  const int z = blockIdx.z;
  if (z == 2) {
    gemm16_gll<f16>(Ym, vwT, vb, Vm, m0, n0, (f16(*)[128][32]) & sm4[0][0][0][0],
                    (f16(*)[128][32]) & sm4[0][2][0][0]);
    return;
  }
  const short* Agh = z ? Yh : Xh;
  const short* Agl = z ? Yl : Xl;
  const short* Wh = z ? kwh : qwh;
  const short* Wl = z ? kwl : qwl;
  const float* bias = z ? kbias : qb;
  short* Ch = z ? Kh : Qh;
  short* Cl = z ? Kl : Ql;
  const float osc = z ? 1.f : (float)QPROJ_SCALE;  // Q pre-scaled for attn

  const int tid = threadIdx.x;
  const int wv = tid >> 6, lane = tid & 63;
  const int wm = wv >> 1, wn = wv & 1;
  const int l15 = lane & 15, lg = lane >> 4;
  const int srow = lane >> 2, sslot = lane & 3;

  // wave wv stages stream wv: 0=A-hi, 1=A-lo, 2=B-hi, 3=B-lo (8 KB each)
  const short* gsb = (wv == 0) ? Agh : (wv == 1) ? Agl : (wv == 2) ? Wh : Wl;
  const int rb = (wv < 2) ? m0 : n0;

  const f32x4 fz = {0.f, 0.f, 0.f, 0.f};
  f32x4 acc[4][4];
#pragma unroll
  for (int m = 0; m < 4; ++m)
#pragma unroll
    for (int n = 0; n < 4; ++n) acc[m][n] = fz;

  PSTAGE(0, 0);  // prologue
  int cur = 0;
  for (int k0 = 0; k0 < 512; k0 += 32) {
    __syncthreads();  // drains prefetch -> buf[cur] ready; prev reads done
    if (k0 < 480) PSTAGE(cur ^ 1, k0 + 32);  // in flight under compute
    bf16x8 afh[4], afl[4], bfh[4], bfl[4];
#pragma unroll
    for (int m = 0; m < 4; ++m) {
      const int r = wm * 64 + m * 16 + l15;
      const int sl = (lg ^ ((r >> 1) & 3)) * 8;
      afh[m] = *(const bf16x8*)&sm4[cur][0][r][sl];
      afl[m] = *(const bf16x8*)&sm4[cur][1][r][sl];
    }
#pragma unroll
    for (int n = 0; n < 4; ++n) {
      const int r = wn * 64 + n * 16 + l15;
      const int sl = (lg ^ ((r >> 1) & 3)) * 8;
      bfh[n] = *(const bf16x8*)&sm4[cur][2][r][sl];
      bfl[n] = *(const bf16x8*)&sm4[cur][3][r][sl];
    }
#pragma unroll
    for (int m = 0; m < 4; ++m)
#pragma unroll
      for (int n = 0; n < 4; ++n) {
        acc[m][n] = MFMAB16(afh[m], bfh[n], acc[m][n]);
        acc[m][n] = MFMAB16(afh[m], bfl[n], acc[m][n]);
        acc[m][n] = MFMAB16(afl[m], bfh[n], acc[m][n]);
      }
    cur ^= 1;
  }
  // epilogue: split-bf16 output (+ deterministic K column partial sums)
  float csum[4];
#pragma unroll
  for (int n = 0; n < 4; ++n) {
    const int col = n0 + wn * 64 + n * 16 + l15;
    const float b = bias[col];
    csum[n] = 16.f * b;
#pragma unroll
    for (int m = 0; m < 4; ++m) {
      const int row = m0 + wm * 64 + m * 16 + lg * 4;
#pragma unroll
      for (int r = 0; r < 4; ++r) {
        const float vraw = acc[m][n][r] + b;
        csum[n] += acc[m][n][r];
        short h, l;
        splitbf(vraw * osc, h, l);
        const size_t idx = (size_t)(row + r) * 512 + col;
        Ch[idx] = h;
        Cl[idx] = l;
      }
    }
  }
  if (z == 1) {
    // block-local column reduction (deterministic): 128 cols x 8 contributors
    float* cred = (float*)&sm4[0][0][0][0];
    __syncthreads();  // all waves done with LDS tiles
#pragma unroll
    for (int n = 0; n < 4; ++n)
      cred[(wn * 64 + n * 16 + l15) * 8 + wm * 4 + lg] = csum[n];
    __syncthreads();
    if (tid < 64) {
      float s = 0.f;
#pragma unroll
      for (int j = 0; j < 8; ++j)
        s += cred[tid * 8 + j] + cred[(tid + 64) * 8 + j];
      Kpart[((size_t)mt * 4 + nt) * 64 + tid] = s;  // mt == problem p
    }
  }
}

// ----------------------- V transpose (per problem) -------------------------
// Vm [8192][512] f16 -> Vt [64 p][64 dh][1024 k] f16.
__global__ __launch_bounds__(256) void k_vtr(const f16* __restrict__ Vm,
                                             f16* __restrict__ Vt) {
  const int p = blockIdx.y;
  const int j0 = blockIdx.x * 16;
  __shared__ f16 L[16][520];
  const int tid = threadIdx.x;
#pragma unroll
  for (int it = 0; it < 4; ++it) {
    int idx = it * 256 + tid;
    int row = idx >> 6, oct = idx & 63;
    *(f16x8*)&L[row][oct * 8] =
        *(const f16x8*)&Vm[(size_t)(p * 128 + j0 + row) * 512 + oct * 8];
  }
  __syncthreads();
#pragma unroll
  for (int it = 0; it < 4; ++it) {
    int idx = it * 256 + tid;
    int dh = idx >> 4, j = idx & 15;
    f16x8 v;
#pragma unroll
    for (int g = 0; g < 8; ++g) v[g] = L[j][g * 64 + dh];
    *(f16x8*)&Vt[((size_t)p * 64 + dh) * 1024 + (j0 + j) * 8] = v;
  }
}

// ------------------------------- attention ---------------------------------
// grid (64 problems, 8 q-tiles), 512 threads = 8 waves, ONE 16-q group/wave.
// Double-buffered LDS, one barrier per 64-key chunk; setprio around MFMA.
// Threshold mean from Kpart partial sums (x 1/1024).
#define LOADREG(cc)                              \
  {                                              \
    rh = *(const bf16x8*)(KhSrc + (cc) * 4096);  \
    rl = *(const bf16x8*)(KlSrc + (cc) * 4096);  \
    rv = *(const f16x8*)(VSrc + (cc) * 64);      \
  }
#define STOREBUF(b)                      \
  {                                      \
    *(bf16x8*)&KhS[b][skey][sslot] = rh; \
    *(bf16x8*)&KlS[b][skey][sslot] = rl; \
    *(f16x8*)&Vs[b][skey][sslot] = rv;   \
  }

__global__ __launch_bounds__(512, 4) void k_attn(
    const short* __restrict__ Qh, const short* __restrict__ Ql,
    const short* __restrict__ Kh, const short* __restrict__ Kl,
    const f16* __restrict__ Vt, const float* __restrict__ Kpart,
    f16* __restrict__ Om) {
  constexpr int S = 1024, DH = 64;
  const int p = blockIdx.x;
  const int qt = blockIdx.y;
  const size_t pb = (size_t)p * S * DH;
  const short* Qhp = Qh + pb;
  const short* Qlp = Ql + pb;
  const short* Khp = Kh + pb;
  const short* Klp = Kl + pb;
  const f16* Vtp = Vt + pb;  // [64 dh][1024 k]
  f16* Op = Om + pb;

  const int tid = threadIdx.x;
  const int w = tid >> 6, lane = tid & 63;
  const int l15 = lane & 15, lg = lane >> 4;

  __shared__ __align__(16) short KhS[2][64][64];
  __shared__ __align__(16) short KlS[2][64][64];
  __shared__ __align__(16) f16 Vs[2][64][64];  // 48 KB total

  const int skey = tid >> 3;
  const int slot8 = tid & 7;
  const int sslot = (slot8 ^ (skey & 7)) * 8;
  const short* KhSrc = Khp + skey * 64 + slot8 * 8;
  const short* KlSrc = Klp + skey * 64 + slot8 * 8;
  const f16* VSrc = Vtp + (size_t)skey * 1024 + slot8 * 8;

  bf16x8 rh, rl;
  f16x8 rv;
  LOADREG(0);
  STOREBUF(0);  // visible to all after iter-0 barrier
  LOADREG(1);

  // this wave's 16-q group (Q pre-scaled by QPROJ_SCALE)
  const int qrow = qt * 128 + w * 16;
  const size_t qo = (size_t)(qrow + l15) * DH + lg * 8;
  bf16x8 qh0 = *(const bf16x8*)(Qhp + qo);
  bf16x8 ql0 = *(const bf16x8*)(Qlp + qo);
  bf16x8 qh1 = *(const bf16x8*)(Qhp + qo + 32);
  bf16x8 ql1 = *(const bf16x8*)(Qlp + qo + 32);

  // threshold: mean_q = (Qscaled_q . Ksum) / 1024, Ksum = sum of 4 partials
  const float* kp = Kpart + (size_t)p * 256;
  float km0[8], km1[8];
#pragma unroll
  for (int j = 0; j < 8; ++j) { km0[j] = 0.f; km1[j] = 0.f; }
#pragma unroll
  for (int pt = 0; pt < 4; ++pt) {
    const float* bb = kp + pt * 64;
#pragma unroll
    for (int j = 0; j < 8; ++j) {
      km0[j] += bb[lg * 8 + j];
      km1[j] += bb[32 + lg * 8 + j];
    }
  }
  float sm = 0.f;
#pragma unroll
  for (int j = 0; j < 8; ++j) {
    sm += (b2f(qh0[j]) + b2f(ql0[j])) * km0[j] +
          (b2f(qh1[j]) + b2f(ql1[j])) * km1[j];
  }
  sm += __shfl_xor(sm, 16);
  sm += __shfl_xor(sm, 32);
  sm *= (1.f / 1024.f);

  const f32x4 fz = {0.f, 0.f, 0.f, 0.f};
  const f16x4 kones = {(f16)1.f, (f16)1.f, (f16)1.f, (f16)1.f};
  f32x4 oac[4];
#pragma unroll
  for (int d = 0; d < 4; ++d) oac[d] = fz;
  f32x4 od = fz;

  for (int c = 0; c < 16; ++c) {
    __syncthreads();  // buf[c&1] writes (iter c-1) + buf[(c+1)&1] reads done
    const int cb = c & 1;
    if (c < 15) STOREBUF(cb ^ 1);  // regs hold chunk c+1
    if (c < 14) LOADREG(c + 2);
    __builtin_amdgcn_s_setprio(1);
#pragma unroll
    for (int t = 0; t < 4; ++t) {
      const int krow = t * 16 + l15;
      const int ksw = krow & 7;
      bf16x8 kh0 = *(const bf16x8*)&KhS[cb][krow][(lg ^ ksw) * 8];
      bf16x8 kh1 = *(const bf16x8*)&KhS[cb][krow][((4 + lg) ^ ksw) * 8];
      bf16x8 kl0 = *(const bf16x8*)&KlS[cb][krow][(lg ^ ksw) * 8];
      bf16x8 kl1 = *(const bf16x8*)&KlS[cb][krow][((4 + lg) ^ ksw) * 8];
      f32x4 a = fz;
      a = MFMAB16(kh0, qh0, a);
      a = MFMAB16(kh1, qh1, a);
      a = MFMAB16(kh0, ql0, a);
      a = MFMAB16(kl0, qh0, a);
      a = MFMAB16(kh1, ql1, a);
      a = MFMAB16(kl1, qh1, a);
      f16x4 pf;
#pragma unroll
      for (int r = 0; r < 4; ++r) {
        float v = a[r];
        float e = (v > sm) ? EXPFN(v) : 0.f;
        pf[r] = (f16)e;
      }
      od = MFMAPV(kones, pf, od);  // den: ones-column MFMA
#pragma unroll
      for (int d0 = 0; d0 < 4; ++d0) {
        const int vrow = d0 * 16 + l15;
        const int vsw = vrow & 7;
        f16x4 va = *(const f16x4*)&Vs[cb][vrow]
                                     [(((t * 2 + (lg >> 1)) ^ vsw) * 8) +
                                      (lg & 1) * 4];
        oac[d0] = MFMAPV(va, pf, oac[d0]);
      }
    }
    __builtin_amdgcn_s_setprio(0);
  }

  const float inv = 1.f / od[0];  // all 4 regs equal (sum over all k)
#pragma unroll
  for (int d0 = 0; d0 < 4; ++d0) {
    f16x4 o0;
#pragma unroll
    for (int r = 0; r < 4; ++r) o0[r] = (f16)(oac[d0][r] * inv);
    *(f16x4*)&Op[(size_t)(qrow + l15) * DH + d0 * 16 + lg * 4] = o0;
  }
}

// ------------------------------- launcher ----------------------------------
extern "C" void kernel_launch(void* const* d_in, const int* in_sizes, int n_in,
                              void* d_out, int out_size, void* d_ws,
                              size_t ws_size, hipStream_t stream) {
  const float* x = (const float*)d_in[0];
  const float* y = (const float*)d_in[1];
  const float* qw = (const float*)d_in[2];
  const float* qb = (const float*)d_in[3];
  const float* kw = (const float*)d_in[4];
  const float* kbias = (const float*)d_in[5];
  const float* vw = (const float*)d_in[6];
  const float* vb = (const float*)d_in[7];
  const float* ow = (const float*)d_in[8];
  const float* ob = (const float*)d_in[9];
  float* out = (float*)d_out;

  char* ws = (char*)d_ws;
  const size_t WT_B = 512ull * 512 * 2;    // 512 KB
  const size_t MAT_B = 8192ull * 512 * 2;  // 8 MB
  short* qwhT = (short*)(ws + 0 * WT_B);
  short* qwlT = (short*)(ws + 1 * WT_B);
  short* kwhT = (short*)(ws + 2 * WT_B);
  short* kwlT = (short*)(ws + 3 * WT_B);
  f16* vwT = (f16*)(ws + 4 * WT_B);
  f16* owT = (f16*)(ws + 5 * WT_B);
  char* m = ws + 6 * WT_B;
  short* Qh = (short*)(m + 0 * MAT_B);
  short* Ql = (short*)(m + 1 * MAT_B);
  short* Kh = (short*)(m + 2 * MAT_B);
  short* Kl = (short*)(m + 3 * MAT_B);
  f16* Vm = (f16*)(m + 4 * MAT_B);
  short* Xh = (short*)(m + 5 * MAT_B);
  short* Xl = (short*)(m + 6 * MAT_B);
  short* Yh = (short*)(m + 7 * MAT_B);
  short* Yl = (short*)(m + 8 * MAT_B);
  f16* Ym = (f16*)(m + 9 * MAT_B);
  float* Kpart = (float*)(m + 10 * MAT_B);  // 64 KB; total ~83.1 MB
  // dead-buffer aliases (stream order makes these safe):
  f16* Vtr = (f16*)Xh;  // k_vtr runs after k_proj (Xh consumed)
  f16* Om = (f16*)Yh;   // k_attn runs after k_proj (Yh consumed)

  hipLaunchKernelGGL(k_wt, dim3(16, 16, 4), dim3(32, 8), 0, stream, qw, kw, vw,
                     ow, qwhT, qwlT, kwhT, kwlT, vwT, owT);
  hipLaunchKernelGGL(k_split, dim3(2048, 2), dim3(256), 0, stream, x, y, Xh,
                     Xl, Yh, Yl, Ym);
  hipLaunchKernelGGL(k_proj, dim3(4, 64, 3), dim3(256), 0, stream, Xh, Xl, Yh,
                     Yl, Ym, qwhT, qwlT, kwhT, kwlT, vwT, qb, kbias, vb, Qh,
                     Ql, Kh, Kl, Vm, Kpart);
  hipLaunchKernelGGL(k_vtr, dim3(8, 64), dim3(256), 0, stream, Vm, Vtr);
  hipLaunchKernelGGL(k_attn, dim3(64, 8), dim3(512), 0, stream, Qh, Ql, Kh, Kl,
                     Vtr, Kpart, Om);
  hipLaunchKernelGGL(k_gemm_out, dim3(4, 64), dim3(256), 0, stream, Om, owT,
                     ob, out);
}